// Round 9
// baseline (746.134 us; speedup 1.0000x reference)
//
#include <hip/hip_runtime.h>
#include <math.h>

#define BATCH 4096

__device__ __forceinline__ void dot4a(float& acc, const float4 v, const float4 wt) {
    acc = fmaf(v.x, wt.x, acc);
    acc = fmaf(v.y, wt.y, acc);
    acc = fmaf(v.z, wt.z, acc);
    acc = fmaf(v.w, wt.w, acc);
}

// ======================= weight transpose pre-pass =======================
__global__ __launch_bounds__(256) void tr_kernel(
    const float* __restrict__ w_c2, const float* __restrict__ w_c3,
    const float* __restrict__ w_d1, const float* __restrict__ w_d2,
    const float* __restrict__ w_d3,
    float* __restrict__ wt2, float* __restrict__ wt3,
    float* __restrict__ wtd1, float* __restrict__ wtd2, float* __restrict__ wtd3)
{
    int i = blockIdx.x * 256 + threadIdx.x;
    if (i < 16384) {  // w_c2 [32][32][16] -> wt2[(co*16+tap)*32+ci]
        int ci = i & 31, tap = (i >> 5) & 15, co = i >> 9;
        wt2[i] = w_c2[(co * 32 + ci) * 16 + tap];
    }
    if (i < 18432) {  // w_c3 [64][32][9] -> wt3[(co*9+tap)*32+ci]
        int ci = i & 31, r = i >> 5, tap = r % 9, co = r / 9;
        wt3[i] = w_c3[(co * 32 + ci) * 9 + tap];
    }
    if (i < 18432) {  // w_d1 [64][32][9] -> wtd1[(co*9+tap)*64+ci]
        int ci = i & 63, r = i >> 6, tap = r % 9, co = r / 9;
        wtd1[i] = w_d1[(ci * 32 + co) * 9 + tap];
    }
    if (i < 16384) {  // w_d2 [32][32][16] -> wtd2[(co*16+tap)*32+ci]
        int ci = i & 31, tap = (i >> 5) & 15, co = i >> 9;
        wtd2[i] = w_d2[(ci * 32 + co) * 16 + tap];
    }
    if (i < 512) {    // w_d3 [32][1][16] -> wtd3[tap*32+ci]
        int ci = i & 31, tap = i >> 5;
        wtd3[i] = w_d3[ci * 16 + tap];
    }
}

// ======================= fused encoder (R6 layout + sliding-window conv2) =======================
// Spatially padded stride-36 LDS images (R6 -- best measured); conv2 lanes walk
// a full output row with a 2-column sliding window: 64 reads/row vs 112.
__global__ __launch_bounds__(256, 3) void enc_kernel(
    const float* __restrict__ x,
    const float* __restrict__ w_c1, const float* __restrict__ b_c1,
    const float* __restrict__ wt2, const float* __restrict__ b_c2,
    const float* __restrict__ wt3, const float* __restrict__ b_c3,
    float* __restrict__ h3out)
{
    __shared__ __align__(16) float buf[12708];
    float* s_h1 = buf;            // padded 16x16 rows x 36  (h1: 14x14x32)
    float* s_h3 = buf;            // [1024] aliases h1 after conv2
    float* s_x  = buf + 9216;     // padded 30x30            (x: 28x28)
    float* s_h2 = buf + 10116;    // padded 9x9 rows x 32    (h2: 7x7x32)

    const int n = blockIdx.x, tid = threadIdx.x;
    const int wv = __builtin_amdgcn_readfirstlane((int)(tid >> 6));
    const int lane = tid & 63;
    const int co0 = wv * 8;

    // ---- zero padded regions, stage x interior ----
    {
        float4* z1 = (float4*)buf;
        #pragma unroll
        for (int i = tid; i < 2304; i += 256) z1[i] = make_float4(0.f, 0.f, 0.f, 0.f);
        float4* z2 = (float4*)(buf + 10116);
        for (int i = tid; i < 648; i += 256) z2[i] = make_float4(0.f, 0.f, 0.f, 0.f);
        for (int i = tid; i < 30; i += 256) { s_x[i] = 0.f; s_x[870 + i] = 0.f; }
        for (int i = tid; i < 28; i += 256) { s_x[(i + 1) * 30] = 0.f; s_x[(i + 1) * 30 + 29] = 0.f; }
        for (int i = tid; i < 784; i += 256) {
            int iy = i / 28, ix = i - iy * 28;
            s_x[(iy + 1) * 30 + ix + 1] = x[(size_t)n * 784 + i];
        }
    }
    __syncthreads();

    // ---- conv1: 1->32, k4 s2 p1, 28x28 -> 14x14, relu ----
    {
        const int poff = lane & 15, pr = lane >> 4;
        const int ca = co0 + pr * 2;
        float w1a[16], w1b[16];
        #pragma unroll
        for (int k = 0; k < 4; ++k) {
            *(float4*)&w1a[4 * k] = *(const float4*)(w_c1 + ca * 16 + 4 * k);
            *(float4*)&w1b[4 * k] = *(const float4*)(w_c1 + (ca + 1) * 16 + 4 * k);
        }
        const float ba = b_c1[ca], bb = b_c1[ca + 1];
        for (int t = 0; t < 13; ++t) {
            int pos = poff + 16 * t;
            bool val = pos < 196;
            int p = val ? pos : 0;
            int oy = p / 14, ox = p - oy * 14;
            const float* bp = s_x + (2 * oy) * 30 + 2 * ox;
            float a0 = ba, a1 = bb;
            #pragma unroll
            for (int ky = 0; ky < 4; ++ky)
                #pragma unroll
                for (int kx = 0; kx < 4; ++kx) {
                    float v = bp[ky * 30 + kx];
                    a0 = fmaf(v, w1a[ky * 4 + kx], a0);
                    a1 = fmaf(v, w1b[ky * 4 + kx], a1);
                }
            if (val)
                *(float2*)(s_h1 + ((oy + 1) * 16 + ox + 1) * 36 + ca) =
                    make_float2(fmaxf(a0, 0.f), fmaxf(a1, 0.f));
        }
    }
    __syncthreads();

    // ---- conv2: 32->32, k4 s2 p1, 14x14 -> 7x7, relu (sliding window) ----
    // lane = rh(1b) | pair(2b) | cig(3b). Each lane walks a full output row;
    // consecutive ox share 2 of 4 input columns per ky.
    {
        const int rh = lane & 1, pr = (lane >> 1) & 3, cig = lane >> 3;
        const int ca = co0 + pr * 2;
        float4 w2a[16], w2b[16];
        #pragma unroll
        for (int t = 0; t < 16; ++t) {
            w2a[t] = *(const float4*)(wt2 + (ca * 16 + t) * 32 + cig * 4);
            w2b[t] = *(const float4*)(wt2 + ((ca + 1) * 16 + t) * 32 + cig * 4);
        }
        const float ba = b_c2[ca], bb = b_c2[ca + 1];
        for (int r = 0; r < 4; ++r) {
            int oy = rh * 4 + r;
            bool rowval = oy < 7;
            int oyc = rowval ? oy : 0;
            // padded rows 2*oyc + ky (ky 0..3), padded cols 2*ox + kx
            const float* rowp = s_h1 + (2 * oyc) * 16 * 36 + cig * 4;
            float4 win[4][4];
            #pragma unroll
            for (int ky = 0; ky < 4; ++ky)
                #pragma unroll
                for (int c = 0; c < 4; ++c)
                    win[ky][c] = *(const float4*)(rowp + (ky * 16 + c) * 36);
            #pragma unroll
            for (int ox = 0; ox < 7; ++ox) {
                float a0 = 0.f, a1 = 0.f;
                #pragma unroll
                for (int ky = 0; ky < 4; ++ky)
                    #pragma unroll
                    for (int kx = 0; kx < 4; ++kx) {
                        dot4a(a0, win[ky][kx], w2a[ky * 4 + kx]);
                        dot4a(a1, win[ky][kx], w2b[ky * 4 + kx]);
                    }
                a0 += __shfl_xor(a0, 8);  a1 += __shfl_xor(a1, 8);
                a0 += __shfl_xor(a0, 16); a1 += __shfl_xor(a1, 16);
                a0 += __shfl_xor(a0, 32); a1 += __shfl_xor(a1, 32);
                if (cig == 0 && rowval)
                    *(float2*)(s_h2 + ((oy + 1) * 9 + ox + 1) * 32 + ca) =
                        make_float2(fmaxf(a0 + ba, 0.f), fmaxf(a1 + bb, 0.f));
                if (ox < 6) {
                    #pragma unroll
                    for (int ky = 0; ky < 4; ++ky) {
                        win[ky][0] = win[ky][2];
                        win[ky][1] = win[ky][3];
                        win[ky][2] = *(const float4*)(rowp + (ky * 16 + 2 * ox + 4) * 36);
                        win[ky][3] = *(const float4*)(rowp + (ky * 16 + 2 * ox + 5) * 36);
                    }
                }
            }
        }
    }
    __syncthreads();

    // ---- conv3: 32->64, k3 s2 p1, 7x7 -> 4x4, relu ----
    {
        const int pr = lane & 7, cig = lane >> 3;
        const int ca = wv * 16 + pr * 2;
        float4 w3a[9], w3b[9];
        #pragma unroll
        for (int t = 0; t < 9; ++t) {
            w3a[t] = *(const float4*)(wt3 + (ca * 9 + t) * 32 + cig * 4);
            w3b[t] = *(const float4*)(wt3 + ((ca + 1) * 9 + t) * 32 + cig * 4);
        }
        const float ba = b_c3[ca], bb = b_c3[ca + 1];
        #pragma unroll 2
        for (int pos = 0; pos < 16; ++pos) {
            int oy = pos >> 2, ox = pos & 3;
            const float* bp = s_h2 + ((2 * oy) * 9 + 2 * ox) * 32 + cig * 4;
            float a0 = 0.f, a1 = 0.f;
            #pragma unroll
            for (int ky = 0; ky < 3; ++ky)
                #pragma unroll
                for (int kx = 0; kx < 3; ++kx) {
                    float4 v = *(const float4*)(bp + (ky * 9 + kx) * 32);
                    dot4a(a0, v, w3a[ky * 3 + kx]);
                    dot4a(a1, v, w3b[ky * 3 + kx]);
                }
            a0 += __shfl_xor(a0, 8);  a1 += __shfl_xor(a1, 8);
            a0 += __shfl_xor(a0, 16); a1 += __shfl_xor(a1, 16);
            a0 += __shfl_xor(a0, 32); a1 += __shfl_xor(a1, 32);
            if (cig == 0) {
                s_h3[ca * 16 + pos] = fmaxf(a0 + ba, 0.f);
                s_h3[(ca + 1) * 16 + pos] = fmaxf(a1 + bb, 0.f);
            }
        }
    }
    __syncthreads();
    for (int i = tid; i < 1024; i += 256) h3out[(size_t)n * 1024 + i] = s_h3[i];
}

// ======================= tiled NT SGEMM (R6: 256 thr, 64x64, BK=16) =======================
template <bool RELU>
__global__ __launch_bounds__(256) void gemm_nt(
    const float* __restrict__ A, const float* __restrict__ W,
    const float* __restrict__ bias, float* __restrict__ C,
    int M, int N, int K)
{
    __shared__ float As[16][65];
    __shared__ float Ws[16][65];
    const int tid = threadIdx.x;
    const int col0 = blockIdx.x * 64;
    const int row0 = blockIdx.y * 64;
    const int tx = tid & 15, ty = tid >> 4;
    const int lr = tid >> 2, lc = (tid & 3) * 4;
    float acc[4][4] = {};

    for (int k0 = 0; k0 < K; k0 += 16) {
        float4 av = *(const float4*)(A + (size_t)(row0 + lr) * K + k0 + lc);
        float4 wv = *(const float4*)(W + (size_t)(col0 + lr) * K + k0 + lc);
        As[lc + 0][lr] = av.x; As[lc + 1][lr] = av.y; As[lc + 2][lr] = av.z; As[lc + 3][lr] = av.w;
        Ws[lc + 0][lr] = wv.x; Ws[lc + 1][lr] = wv.y; Ws[lc + 2][lr] = wv.z; Ws[lc + 3][lr] = wv.w;
        __syncthreads();
        #pragma unroll
        for (int kk = 0; kk < 16; ++kk) {
            float a[4], b[4];
            #pragma unroll
            for (int i = 0; i < 4; ++i) a[i] = As[kk][ty * 4 + i];
            #pragma unroll
            for (int j = 0; j < 4; ++j) b[j] = Ws[kk][tx * 4 + j];
            #pragma unroll
            for (int i = 0; i < 4; ++i)
                #pragma unroll
                for (int j = 0; j < 4; ++j)
                    acc[i][j] = fmaf(a[i], b[j], acc[i][j]);
        }
        __syncthreads();
    }
    #pragma unroll
    for (int i = 0; i < 4; ++i) {
        int row = row0 + ty * 4 + i;
        float* cp = C + (size_t)row * N + col0 + tx * 4;
        float4 v;
        v.x = acc[i][0] + bias[col0 + tx * 4 + 0];
        v.y = acc[i][1] + bias[col0 + tx * 4 + 1];
        v.z = acc[i][2] + bias[col0 + tx * 4 + 2];
        v.w = acc[i][3] + bias[col0 + tx * 4 + 3];
        if (RELU) {
            v.x = fmaxf(v.x, 0.f); v.y = fmaxf(v.y, 0.f);
            v.z = fmaxf(v.z, 0.f); v.w = fmaxf(v.w, 0.f);
        }
        *(float4*)cp = v;
    }
}

// ======= fused mu/logvar heads + 100-step reversing + reparameterize =======
__global__ __launch_bounds__(256) void mulsrev_kernel(
    const float* __restrict__ h,
    const float* __restrict__ w_mu, const float* __restrict__ b_mu,
    const float* __restrict__ w_ls, const float* __restrict__ b_ls,
    const float* __restrict__ eps,
    float* __restrict__ mu_out, float* __restrict__ ls_out, float* __restrict__ z)
{
    int idx = blockIdx.x * 256 + threadIdx.x;
    if (idx >= BATCH * 20) return;
    int i = idx / 20, j = idx - i * 20;
    const float4* hp = (const float4*)(h + (size_t)i * 256);
    const float4* mp = (const float4*)(w_mu + j * 256);
    const float4* lp = (const float4*)(w_ls + j * 256);
    float am = b_mu[j], al = b_ls[j];
    #pragma unroll 8
    for (int k = 0; k < 64; ++k) {
        float4 hv = hp[k], mv = mp[k], lv = lp[k];
        am = fmaf(hv.x, mv.x, am); al = fmaf(hv.x, lv.x, al);
        am = fmaf(hv.y, mv.y, am); al = fmaf(hv.y, lv.y, al);
        am = fmaf(hv.z, mv.z, am); al = fmaf(hv.z, lv.z, al);
        am = fmaf(hv.w, mv.w, am); al = fmaf(hv.w, lv.w, al);
    }
    mu_out[idx] = am;
    ls_out[idx] = al;
    double m = (double)am;
    float s = al;
    #pragma unroll 4
    for (int t = 0; t < 100; ++t) {
        m += 0.1 * m;
        s += 0.05f * (expf(s) - 1.f);
    }
    z[idx] = fmaf(eps[idx], expf(0.5f * s), (float)m);
}

// ======================= fc2: [B,20] -> [B,256], relu =======================
__global__ __launch_bounds__(256) void fc2_kernel(
    const float* __restrict__ z, const float* __restrict__ w, const float* __restrict__ b,
    float* __restrict__ out)
{
    int idx = blockIdx.x * 256 + threadIdx.x;
    int i = idx >> 8, j = idx & 255;
    float acc = b[j];
    const float* zp = z + i * 20;
    const float* wp = w + j * 20;
    #pragma unroll
    for (int k = 0; k < 20; ++k) acc = fmaf(zp[k], wp[k], acc);
    out[idx] = fmaxf(acc, 0.f);
}

// ======================= fused decoder (R6 version) =======================
__global__ __launch_bounds__(256, 3) void dec_kernel(
    const float* __restrict__ hin,
    const float* __restrict__ wtd1, const float* __restrict__ b_d1,
    const float* __restrict__ wtd2, const float* __restrict__ b_d2,
    const float* __restrict__ wtd3, const float* __restrict__ b_d3,
    float* __restrict__ xhat)
{
    __shared__ __align__(16) float dbuf[11060];
    float* s_d2 = dbuf;            // [196 pos][36]  (d2: 14x14x32, no spatial pad)
    float* s_d1 = dbuf + 7056;     // padded 9x9 rows x 36 (d1: 7x7x32)
    float* s_in = dbuf + 9972;     // [16 pos][68]
    float* sP   = dbuf + 7056;     // P[16 taps][196 pos] aliases s_d1+s_in after deconv2

    const int n = blockIdx.x, tid = threadIdx.x;
    const int wv = __builtin_amdgcn_readfirstlane((int)(tid >> 6));
    const int lane = tid & 63;
    const int co0 = wv * 8;

    {
        float4* z1 = (float4*)(dbuf + 7056);
        for (int i = tid; i < 729; i += 256) z1[i] = make_float4(0.f, 0.f, 0.f, 0.f);
        for (int t = tid; t < 1024; t += 256) {
            int c = t & 63, p = t >> 6;
            s_in[p * 68 + c] = hin[(size_t)n * 1024 + c * 16 + p];
        }
    }
    __syncthreads();

    // ---- deconv1: ConvT 64->32 k3 s2 p1, 4x4 -> 7x7, relu ----
    {
        const int cig = lane & 7, pq = (lane >> 3) & 1, poff = lane >> 4;
        const int ci0 = cig * 8;
        const int ca = co0 + pq * 4;
        float bd[4];
        #pragma unroll
        for (int u = 0; u < 4; ++u) bd[u] = b_d1[ca + u];

        #pragma unroll
        for (int py = 0; py < 2; ++py) {
            #pragma unroll
            for (int px = 0; px < 2; ++px) {
                const int ny = 4 - py, nx = 4 - px;
                const int P = ny * nx;
                const int na = py ? 2 : 1, nb = px ? 2 : 1;
                float4 wd[4][2][2][2];
                #pragma unroll
                for (int u = 0; u < 4; ++u)
                    #pragma unroll
                    for (int a = 0; a < 2; ++a) {
                        if (a >= na) continue;
                        #pragma unroll
                        for (int b = 0; b < 2; ++b) {
                            if (b >= nb) continue;
                            int ky = py ? (a ? 2 : 0) : 1;
                            int kx = px ? (b ? 2 : 0) : 1;
                            const float* wp = wtd1 + ((ca + u) * 9 + ky * 3 + kx) * 64 + ci0;
                            wd[u][a][b][0] = *(const float4*)(wp);
                            wd[u][a][b][1] = *(const float4*)(wp + 4);
                        }
                    }
                const int niter = (P + 3) >> 2;
                for (int it = 0; it < niter; ++it) {
                    int pidx = it * 4 + poff;
                    bool act = pidx < P;
                    int p = act ? pidx : 0;
                    int sy = p / nx, sx = p - sy * nx;
                    float acc[4] = {};
                    #pragma unroll
                    for (int a = 0; a < 2; ++a) {
                        if (a >= na) continue;
                        int iy = py ? (a ? sy : sy + 1) : sy;
                        #pragma unroll
                        for (int b = 0; b < 2; ++b) {
                            if (b >= nb) continue;
                            int ix = px ? (b ? sx : sx + 1) : sx;
                            const float* bp = s_in + (iy * 4 + ix) * 68 + ci0;
                            float4 v0 = *(const float4*)(bp);
                            float4 v1 = *(const float4*)(bp + 4);
                            #pragma unroll
                            for (int u = 0; u < 4; ++u) {
                                dot4a(acc[u], v0, wd[u][a][b][0]);
                                dot4a(acc[u], v1, wd[u][a][b][1]);
                            }
                        }
                    }
                    #pragma unroll
                    for (int u = 0; u < 4; ++u) {
                        acc[u] += __shfl_xor(acc[u], 1);
                        acc[u] += __shfl_xor(acc[u], 2);
                        acc[u] += __shfl_xor(acc[u], 4);
                    }
                    if (cig == 0 && act) {
                        int oy = 2 * sy + py, ox = 2 * sx + px;
                        float4 o;
                        o.x = fmaxf(acc[0] + bd[0], 0.f);
                        o.y = fmaxf(acc[1] + bd[1], 0.f);
                        o.z = fmaxf(acc[2] + bd[2], 0.f);
                        o.w = fmaxf(acc[3] + bd[3], 0.f);
                        *(float4*)(s_d1 + ((oy + 1) * 9 + ox + 1) * 36 + ca) = o;
                    }
                }
            }
        }
    }
    __syncthreads();

    // ---- deconv2: ConvT 32->32 k4 s2 p1, 7x7 -> 14x14, relu ----
    {
        const int cig = lane & 3, pq = (lane >> 2) & 1;
        const int py = (lane >> 3) & 1, px = (lane >> 4) & 1, poff = lane >> 5;
        const int ci0 = cig * 8;
        const int ca = co0 + pq * 4;
        float4 w2[4][2][2][2];
        float bd[4];
        #pragma unroll
        for (int u = 0; u < 4; ++u) {
            bd[u] = b_d2[ca + u];
            #pragma unroll
            for (int a = 0; a < 2; ++a)
                #pragma unroll
                for (int b = 0; b < 2; ++b) {
                    int ky = py ? (a ? 2 : 0) : (a ? 3 : 1);
                    int kx = px ? (b ? 2 : 0) : (b ? 3 : 1);
                    const float* wp = wtd2 + ((ca + u) * 16 + ky * 4 + kx) * 32 + ci0;
                    w2[u][a][b][0] = *(const float4*)(wp);
                    w2[u][a][b][1] = *(const float4*)(wp + 4);
                }
        }
        for (int it = 0; it < 25; ++it) {
            int pidx = it * 2 + poff;
            bool act = pidx < 49;
            int sp = act ? pidx : 0;
            int sy = sp / 7, sx = sp - sy * 7;
            float acc[4] = {};
            #pragma unroll
            for (int a = 0; a < 2; ++a) {
                int iy = py ? (a ? sy : sy + 1) : (a ? sy - 1 : sy);
                #pragma unroll
                for (int b = 0; b < 2; ++b) {
                    int ix = px ? (b ? sx : sx + 1) : (b ? sx - 1 : sx);
                    const float* bp = s_d1 + ((iy + 1) * 9 + ix + 1) * 36 + ci0;
                    float4 v0 = *(const float4*)(bp);
                    float4 v1 = *(const float4*)(bp + 4);
                    #pragma unroll
                    for (int u = 0; u < 4; ++u) {
                        dot4a(acc[u], v0, w2[u][a][b][0]);
                        dot4a(acc[u], v1, w2[u][a][b][1]);
                    }
                }
            }
            #pragma unroll
            for (int u = 0; u < 4; ++u) {
                acc[u] += __shfl_xor(acc[u], 1);
                acc[u] += __shfl_xor(acc[u], 2);
            }
            if (cig == 0 && act) {
                int oy = 2 * sy + py, ox = 2 * sx + px;
                float4 o;
                o.x = fmaxf(acc[0] + bd[0], 0.f);
                o.y = fmaxf(acc[1] + bd[1], 0.f);
                o.z = fmaxf(acc[2] + bd[2], 0.f);
                o.w = fmaxf(acc[3] + bd[3], 0.f);
                *(float4*)(s_d2 + (oy * 14 + ox) * 36 + ca) = o;
            }
        }
    }
    __syncthreads();

    // ---- deconv3 phase 1: P[t][pos] = sum_ci d2[ci,pos] * w3[ci,t] ----
    {
        const int pp = lane & 15, tq = lane >> 4;
        float4 w3[4][8];
        #pragma unroll
        for (int j = 0; j < 4; ++j)
            #pragma unroll
            for (int q = 0; q < 8; ++q)
                w3[j][q] = *(const float4*)(wtd3 + (tq * 4 + j) * 32 + q * 4);
        #pragma unroll
        for (int r = 0; r < 4; ++r) {
            int p = r * 64 + wv * 16 + pp;
            if (p < 196) {
                const float* bp = s_d2 + p * 36;
                float4 v[8];
                #pragma unroll
                for (int q = 0; q < 8; ++q) v[q] = *(const float4*)(bp + q * 4);
                #pragma unroll
                for (int j = 0; j < 4; ++j) {
                    float acc = 0.f;
                    #pragma unroll
                    for (int q = 0; q < 8; ++q) dot4a(acc, v[q], w3[j][q]);
                    sP[(tq * 4 + j) * 196 + p] = acc;
                }
            }
        }
    }
    __syncthreads();

    // ---- deconv3 phase 2: x_hat = sigmoid(b + 4 masked P lookups) ----
    {
        const float bd3 = b_d3[0];
        #pragma unroll
        for (int t = 0; t < 4; ++t) {
            int o = t * 256 + tid;
            if (o < 784) {
                int oy = o / 28, ox = o - oy * 28;
                int py = oy & 1, px = ox & 1, sy = oy >> 1, sx = ox >> 1;
                float acc = bd3;
                #pragma unroll
                for (int a = 0; a < 2; ++a) {
                    int ky = py ? (a ? 2 : 0) : (a ? 3 : 1);
                    int iy = py ? (a ? sy : sy + 1) : (a ? sy - 1 : sy);
                    bool vy = (unsigned)iy < 14u;
                    #pragma unroll
                    for (int b = 0; b < 2; ++b) {
                        int kx = px ? (b ? 2 : 0) : (b ? 3 : 1);
                        int ix = px ? (b ? sx : sx + 1) : (b ? sx - 1 : sx);
                        if (vy && (unsigned)ix < 14u)
                            acc += sP[(ky * 4 + kx) * 196 + iy * 14 + ix];
                    }
                }
                xhat[(size_t)n * 784 + o] = 1.f / (1.f + expf(-acc));
            }
        }
    }
}

extern "C" void kernel_launch(void* const* d_in, const int* in_sizes, int n_in,
                              void* d_out, int out_size, void* d_ws, size_t ws_size,
                              hipStream_t stream) {
    const float* x     = (const float*)d_in[0];
    const float* eps   = (const float*)d_in[1];
    const float* w_c1  = (const float*)d_in[2];
    const float* b_c1  = (const float*)d_in[3];
    const float* w_c2  = (const float*)d_in[4];
    const float* b_c2  = (const float*)d_in[5];
    const float* w_c3  = (const float*)d_in[6];
    const float* b_c3  = (const float*)d_in[7];
    const float* w_fc1 = (const float*)d_in[8];
    const float* b_fc1 = (const float*)d_in[9];
    const float* w_mu  = (const float*)d_in[10];
    const float* b_mu  = (const float*)d_in[11];
    const float* w_ls  = (const float*)d_in[12];
    const float* b_ls  = (const float*)d_in[13];
    const float* w_fc2 = (const float*)d_in[14];
    const float* b_fc2 = (const float*)d_in[15];
    const float* w_fc3 = (const float*)d_in[16];
    const float* b_fc3 = (const float*)d_in[17];
    const float* w_d1  = (const float*)d_in[18];
    const float* b_d1  = (const float*)d_in[19];
    const float* w_d2  = (const float*)d_in[20];
    const float* b_d2  = (const float*)d_in[21];
    const float* w_d3  = (const float*)d_in[22];
    const float* b_d3  = (const float*)d_in[23];

    float* out = (float*)d_out;
    float* x_hat  = out;                  // 4096*784
    float* mu_out = out + 4096 * 784;     // 4096*20
    float* ls_out = mu_out + 4096 * 20;   // 4096*20

    float* buf1 = (float*)d_ws;           // 4096*1024 (h3 / fc3 out); zlat reuses head
    float* buf2 = buf1 + 4096 * 1024;     // 4096*256  (fc1 out / fc2 out)
    float* zlat = buf1;                   // 4096*20, live only between mulsrev and fc2
    float* wt2  = buf2 + 4096 * 256;      // 16384
    float* wt3  = wt2 + 16384;            // 18432
    float* wtd1 = wt3 + 18432;            // 18432
    float* wtd2 = wtd1 + 18432;           // 16384
    float* wtd3 = wtd2 + 16384;           // 512

    tr_kernel<<<72, 256, 0, stream>>>(w_c2, w_c3, w_d1, w_d2, w_d3, wt2, wt3, wtd1, wtd2, wtd3);
    enc_kernel<<<BATCH, 256, 0, stream>>>(x, w_c1, b_c1, wt2, b_c2, wt3, b_c3, buf1);
    gemm_nt<true><<<dim3(256 / 64, BATCH / 64), 256, 0, stream>>>(buf1, w_fc1, b_fc1, buf2, BATCH, 256, 1024);
    mulsrev_kernel<<<(BATCH * 20) / 256, 256, 0, stream>>>(buf2, w_mu, b_mu, w_ls, b_ls, eps, mu_out, ls_out, zlat);
    fc2_kernel<<<BATCH, 256, 0, stream>>>(zlat, w_fc2, b_fc2, buf2);
    gemm_nt<true><<<dim3(1024 / 64, BATCH / 64), 256, 0, stream>>>(buf2, w_fc3, b_fc3, buf1, BATCH, 1024, 256);
    dec_kernel<<<BATCH, 256, 0, stream>>>(buf1, wtd1, b_d1, wtd2, b_d2, wtd3, b_d3, x_hat);
}

// Round 10
// 642.749 us; speedup vs baseline: 1.1608x; 1.1608x over previous
//
#include <hip/hip_runtime.h>
#include <math.h>

#define BATCH 4096

__device__ __forceinline__ void dot4a(float& acc, const float4 v, const float4 wt) {
    acc = fmaf(v.x, wt.x, acc);
    acc = fmaf(v.y, wt.y, acc);
    acc = fmaf(v.z, wt.z, acc);
    acc = fmaf(v.w, wt.w, acc);
}

// ======================= weight transpose pre-pass =======================
__global__ __launch_bounds__(256) void tr_kernel(
    const float* __restrict__ w_c2, const float* __restrict__ w_c3,
    const float* __restrict__ w_d1, const float* __restrict__ w_d2,
    const float* __restrict__ w_d3,
    float* __restrict__ wt2, float* __restrict__ wt3,
    float* __restrict__ wtd1, float* __restrict__ wtd2, float* __restrict__ wtd3)
{
    int i = blockIdx.x * 256 + threadIdx.x;
    if (i < 16384) {  // w_c2 [32][32][16] -> wt2[(co*16+tap)*32+ci]
        int ci = i & 31, tap = (i >> 5) & 15, co = i >> 9;
        wt2[i] = w_c2[(co * 32 + ci) * 16 + tap];
    }
    if (i < 18432) {  // w_c3 [64][32][9] -> wt3[(co*9+tap)*32+ci]
        int ci = i & 31, r = i >> 5, tap = r % 9, co = r / 9;
        wt3[i] = w_c3[(co * 32 + ci) * 9 + tap];
    }
    if (i < 18432) {  // w_d1 [64][32][9] -> wtd1[(co*9+tap)*64+ci]
        int ci = i & 63, r = i >> 6, tap = r % 9, co = r / 9;
        wtd1[i] = w_d1[(ci * 32 + co) * 9 + tap];
    }
    if (i < 16384) {  // w_d2 [32][32][16] -> wtd2[(co*16+tap)*32+ci]
        int ci = i & 31, tap = (i >> 5) & 15, co = i >> 9;
        wtd2[i] = w_d2[(ci * 32 + co) * 16 + tap];
    }
    if (i < 512) {    // w_d3 [32][1][16] -> wtd3[tap*32+ci]
        int ci = i & 31, tap = i >> 5;
        wtd3[i] = w_d3[ci * 16 + tap];
    }
}

// ======================= fused encoder (R6 exact -- best measured 649us) =======================
__global__ __launch_bounds__(256, 3) void enc_kernel(
    const float* __restrict__ x,
    const float* __restrict__ w_c1, const float* __restrict__ b_c1,
    const float* __restrict__ wt2, const float* __restrict__ b_c2,
    const float* __restrict__ wt3, const float* __restrict__ b_c3,
    float* __restrict__ h3out)
{
    __shared__ __align__(16) float buf[12708];
    float* s_h1 = buf;            // padded 16x16 rows x 36  (h1: 14x14x32)
    float* s_h3 = buf;            // [1024] aliases h1 after conv2
    float* s_x  = buf + 9216;     // padded 30x30            (x: 28x28)
    float* s_h2 = buf + 10116;    // padded 9x9 rows x 32    (h2: 7x7x32)

    const int n = blockIdx.x, tid = threadIdx.x;
    const int wv = __builtin_amdgcn_readfirstlane((int)(tid >> 6));
    const int lane = tid & 63;
    const int co0 = wv * 8;

    {
        float4* z1 = (float4*)buf;
        #pragma unroll
        for (int i = tid; i < 2304; i += 256) z1[i] = make_float4(0.f, 0.f, 0.f, 0.f);
        float4* z2 = (float4*)(buf + 10116);
        for (int i = tid; i < 648; i += 256) z2[i] = make_float4(0.f, 0.f, 0.f, 0.f);
        for (int i = tid; i < 30; i += 256) { s_x[i] = 0.f; s_x[870 + i] = 0.f; }
        for (int i = tid; i < 28; i += 256) { s_x[(i + 1) * 30] = 0.f; s_x[(i + 1) * 30 + 29] = 0.f; }
        for (int i = tid; i < 784; i += 256) {
            int iy = i / 28, ix = i - iy * 28;
            s_x[(iy + 1) * 30 + ix + 1] = x[(size_t)n * 784 + i];
        }
    }
    __syncthreads();

    // ---- conv1 ----
    {
        const int poff = lane & 15, pr = lane >> 4;
        const int ca = co0 + pr * 2;
        float w1a[16], w1b[16];
        #pragma unroll
        for (int k = 0; k < 4; ++k) {
            *(float4*)&w1a[4 * k] = *(const float4*)(w_c1 + ca * 16 + 4 * k);
            *(float4*)&w1b[4 * k] = *(const float4*)(w_c1 + (ca + 1) * 16 + 4 * k);
        }
        const float ba = b_c1[ca], bb = b_c1[ca + 1];
        for (int t = 0; t < 13; ++t) {
            int pos = poff + 16 * t;
            bool val = pos < 196;
            int p = val ? pos : 0;
            int oy = p / 14, ox = p - oy * 14;
            const float* bp = s_x + (2 * oy) * 30 + 2 * ox;
            float a0 = ba, a1 = bb;
            #pragma unroll
            for (int ky = 0; ky < 4; ++ky)
                #pragma unroll
                for (int kx = 0; kx < 4; ++kx) {
                    float v = bp[ky * 30 + kx];
                    a0 = fmaf(v, w1a[ky * 4 + kx], a0);
                    a1 = fmaf(v, w1b[ky * 4 + kx], a1);
                }
            if (val)
                *(float2*)(s_h1 + ((oy + 1) * 16 + ox + 1) * 36 + ca) =
                    make_float2(fmaxf(a0, 0.f), fmaxf(a1, 0.f));
        }
    }
    __syncthreads();

    // ---- conv2 ----
    {
        const int parity = lane & 1, pr = (lane >> 1) & 3, cig = lane >> 3;
        const int ca = co0 + pr * 2;
        float4 w2a[16], w2b[16];
        #pragma unroll
        for (int t = 0; t < 16; ++t) {
            w2a[t] = *(const float4*)(wt2 + (ca * 16 + t) * 32 + cig * 4);
            w2b[t] = *(const float4*)(wt2 + ((ca + 1) * 16 + t) * 32 + cig * 4);
        }
        const float ba = b_c2[ca], bb = b_c2[ca + 1];
        for (int t = 0; t < 25; ++t) {
            int pos = parity + 2 * t;
            bool val = pos < 49;
            int p = val ? pos : 0;
            int oy = p / 7, ox = p - oy * 7;
            const float* bp = s_h1 + ((2 * oy) * 16 + 2 * ox) * 36 + cig * 4;
            float a0 = 0.f, a1 = 0.f;
            #pragma unroll
            for (int ky = 0; ky < 4; ++ky)
                #pragma unroll
                for (int kx = 0; kx < 4; ++kx) {
                    float4 v = *(const float4*)(bp + (ky * 16 + kx) * 36);
                    dot4a(a0, v, w2a[ky * 4 + kx]);
                    dot4a(a1, v, w2b[ky * 4 + kx]);
                }
            a0 += __shfl_xor(a0, 8);  a1 += __shfl_xor(a1, 8);
            a0 += __shfl_xor(a0, 16); a1 += __shfl_xor(a1, 16);
            a0 += __shfl_xor(a0, 32); a1 += __shfl_xor(a1, 32);
            if (cig == 0 && val)
                *(float2*)(s_h2 + ((oy + 1) * 9 + ox + 1) * 32 + ca) =
                    make_float2(fmaxf(a0 + ba, 0.f), fmaxf(a1 + bb, 0.f));
        }
    }
    __syncthreads();

    // ---- conv3 ----
    {
        const int pr = lane & 7, cig = lane >> 3;
        const int ca = wv * 16 + pr * 2;
        float4 w3a[9], w3b[9];
        #pragma unroll
        for (int t = 0; t < 9; ++t) {
            w3a[t] = *(const float4*)(wt3 + (ca * 9 + t) * 32 + cig * 4);
            w3b[t] = *(const float4*)(wt3 + ((ca + 1) * 9 + t) * 32 + cig * 4);
        }
        const float ba = b_c3[ca], bb = b_c3[ca + 1];
        #pragma unroll 2
        for (int pos = 0; pos < 16; ++pos) {
            int oy = pos >> 2, ox = pos & 3;
            const float* bp = s_h2 + ((2 * oy) * 9 + 2 * ox) * 32 + cig * 4;
            float a0 = 0.f, a1 = 0.f;
            #pragma unroll
            for (int ky = 0; ky < 3; ++ky)
                #pragma unroll
                for (int kx = 0; kx < 3; ++kx) {
                    float4 v = *(const float4*)(bp + (ky * 9 + kx) * 32);
                    dot4a(a0, v, w3a[ky * 3 + kx]);
                    dot4a(a1, v, w3b[ky * 3 + kx]);
                }
            a0 += __shfl_xor(a0, 8);  a1 += __shfl_xor(a1, 8);
            a0 += __shfl_xor(a0, 16); a1 += __shfl_xor(a1, 16);
            a0 += __shfl_xor(a0, 32); a1 += __shfl_xor(a1, 32);
            if (cig == 0) {
                s_h3[ca * 16 + pos] = fmaxf(a0 + ba, 0.f);
                s_h3[(ca + 1) * 16 + pos] = fmaxf(a1 + bb, 0.f);
            }
        }
    }
    __syncthreads();
    for (int i = tid; i < 1024; i += 256) h3out[(size_t)n * 1024 + i] = s_h3[i];
}

// ======================= tiled NT SGEMM (64x64, 256 thr, BK=16) =======================
template <bool RELU>
__global__ __launch_bounds__(256) void gemm_nt(
    const float* __restrict__ A, const float* __restrict__ W,
    const float* __restrict__ bias, float* __restrict__ C,
    int M, int N, int K)
{
    __shared__ float As[16][65];
    __shared__ float Ws[16][65];
    const int tid = threadIdx.x;
    const int col0 = blockIdx.x * 64;
    const int row0 = blockIdx.y * 64;
    const int tx = tid & 15, ty = tid >> 4;
    const int lr = tid >> 2, lc = (tid & 3) * 4;
    float acc[4][4] = {};

    for (int k0 = 0; k0 < K; k0 += 16) {
        float4 av = *(const float4*)(A + (size_t)(row0 + lr) * K + k0 + lc);
        float4 wv = *(const float4*)(W + (size_t)(col0 + lr) * K + k0 + lc);
        As[lc + 0][lr] = av.x; As[lc + 1][lr] = av.y; As[lc + 2][lr] = av.z; As[lc + 3][lr] = av.w;
        Ws[lc + 0][lr] = wv.x; Ws[lc + 1][lr] = wv.y; Ws[lc + 2][lr] = wv.z; Ws[lc + 3][lr] = wv.w;
        __syncthreads();
        #pragma unroll
        for (int kk = 0; kk < 16; ++kk) {
            float a[4], b[4];
            #pragma unroll
            for (int i = 0; i < 4; ++i) a[i] = As[kk][ty * 4 + i];
            #pragma unroll
            for (int j = 0; j < 4; ++j) b[j] = Ws[kk][tx * 4 + j];
            #pragma unroll
            for (int i = 0; i < 4; ++i)
                #pragma unroll
                for (int j = 0; j < 4; ++j)
                    acc[i][j] = fmaf(a[i], b[j], acc[i][j]);
        }
        __syncthreads();
    }
    #pragma unroll
    for (int i = 0; i < 4; ++i) {
        int row = row0 + ty * 4 + i;
        float* cp = C + (size_t)row * N + col0 + tx * 4;
        float4 v;
        v.x = acc[i][0] + bias[col0 + tx * 4 + 0];
        v.y = acc[i][1] + bias[col0 + tx * 4 + 1];
        v.z = acc[i][2] + bias[col0 + tx * 4 + 2];
        v.w = acc[i][3] + bias[col0 + tx * 4 + 3];
        if (RELU) {
            v.x = fmaxf(v.x, 0.f); v.y = fmaxf(v.y, 0.f);
            v.z = fmaxf(v.z, 0.f); v.w = fmaxf(v.w, 0.f);
        }
        *(float4*)cp = v;
    }
}

// ======================= NT SGEMM, 64x32 tile (for fc1: N=256 -> 512 blocks, 2/CU) =======================
template <bool RELU>
__global__ __launch_bounds__(256) void gemm_nt_bn32(
    const float* __restrict__ A, const float* __restrict__ W,
    const float* __restrict__ bias, float* __restrict__ C,
    int M, int N, int K)
{
    __shared__ float As[16][65];
    __shared__ float Ws[16][33];
    const int tid = threadIdx.x;
    const int col0 = blockIdx.x * 32;
    const int row0 = blockIdx.y * 64;
    const int tx = tid & 7, ty = tid >> 3;      // 8 x 32 thread grid; 2 rows x 4 cols each
    const int lr = tid >> 2, lc = (tid & 3) * 4;
    float acc[2][4] = {};

    for (int k0 = 0; k0 < K; k0 += 16) {
        float4 av = *(const float4*)(A + (size_t)(row0 + lr) * K + k0 + lc);
        As[lc + 0][lr] = av.x; As[lc + 1][lr] = av.y; As[lc + 2][lr] = av.z; As[lc + 3][lr] = av.w;
        if (tid < 128) {
            float4 wv = *(const float4*)(W + (size_t)(col0 + lr) * K + k0 + lc);
            Ws[lc + 0][lr] = wv.x; Ws[lc + 1][lr] = wv.y; Ws[lc + 2][lr] = wv.z; Ws[lc + 3][lr] = wv.w;
        }
        __syncthreads();
        #pragma unroll
        for (int kk = 0; kk < 16; ++kk) {
            float a0 = As[kk][ty * 2], a1 = As[kk][ty * 2 + 1];
            float b[4];
            #pragma unroll
            for (int j = 0; j < 4; ++j) b[j] = Ws[kk][tx * 4 + j];
            #pragma unroll
            for (int j = 0; j < 4; ++j) {
                acc[0][j] = fmaf(a0, b[j], acc[0][j]);
                acc[1][j] = fmaf(a1, b[j], acc[1][j]);
            }
        }
        __syncthreads();
    }
    #pragma unroll
    for (int i = 0; i < 2; ++i) {
        int row = row0 + ty * 2 + i;
        float* cp = C + (size_t)row * N + col0 + tx * 4;
        float4 v;
        v.x = acc[i][0] + bias[col0 + tx * 4 + 0];
        v.y = acc[i][1] + bias[col0 + tx * 4 + 1];
        v.z = acc[i][2] + bias[col0 + tx * 4 + 2];
        v.w = acc[i][3] + bias[col0 + tx * 4 + 3];
        if (RELU) {
            v.x = fmaxf(v.x, 0.f); v.y = fmaxf(v.y, 0.f);
            v.z = fmaxf(v.z, 0.f); v.w = fmaxf(v.w, 0.f);
        }
        *(float4*)cp = v;
    }
}

// ======= fused mu/logvar heads + 100-step reversing + reparameterize =======
__global__ __launch_bounds__(256) void mulsrev_kernel(
    const float* __restrict__ h,
    const float* __restrict__ w_mu, const float* __restrict__ b_mu,
    const float* __restrict__ w_ls, const float* __restrict__ b_ls,
    const float* __restrict__ eps,
    float* __restrict__ mu_out, float* __restrict__ ls_out, float* __restrict__ z)
{
    int idx = blockIdx.x * 256 + threadIdx.x;
    if (idx >= BATCH * 20) return;
    int i = idx / 20, j = idx - i * 20;
    const float4* hp = (const float4*)(h + (size_t)i * 256);
    const float4* mp = (const float4*)(w_mu + j * 256);
    const float4* lp = (const float4*)(w_ls + j * 256);
    float am = b_mu[j], al = b_ls[j];
    #pragma unroll 8
    for (int k = 0; k < 64; ++k) {
        float4 hv = hp[k], mv = mp[k], lv = lp[k];
        am = fmaf(hv.x, mv.x, am); al = fmaf(hv.x, lv.x, al);
        am = fmaf(hv.y, mv.y, am); al = fmaf(hv.y, lv.y, al);
        am = fmaf(hv.z, mv.z, am); al = fmaf(hv.z, lv.z, al);
        am = fmaf(hv.w, mv.w, am); al = fmaf(hv.w, lv.w, al);
    }
    mu_out[idx] = am;
    ls_out[idx] = al;
    double m = (double)am;
    float s = al;
    #pragma unroll 4
    for (int t = 0; t < 100; ++t) {
        m += 0.1 * m;
        s += 0.05f * (expf(s) - 1.f);
    }
    z[idx] = fmaf(eps[idx], expf(0.5f * s), (float)m);
}

// ======================= fc2: [B,20] -> [B,256], relu =======================
__global__ __launch_bounds__(256) void fc2_kernel(
    const float* __restrict__ z, const float* __restrict__ w, const float* __restrict__ b,
    float* __restrict__ out)
{
    int idx = blockIdx.x * 256 + threadIdx.x;
    int i = idx >> 8, j = idx & 255;
    float acc = b[j];
    const float* zp = z + i * 20;
    const float* wp = w + j * 20;
    #pragma unroll
    for (int k = 0; k < 20; ++k) acc = fmaf(zp[k], wp[k], acc);
    out[idx] = fmaxf(acc, 0.f);
}

// ======================= fused decoder (R6 exact) =======================
__global__ __launch_bounds__(256, 3) void dec_kernel(
    const float* __restrict__ hin,
    const float* __restrict__ wtd1, const float* __restrict__ b_d1,
    const float* __restrict__ wtd2, const float* __restrict__ b_d2,
    const float* __restrict__ wtd3, const float* __restrict__ b_d3,
    float* __restrict__ xhat)
{
    __shared__ __align__(16) float dbuf[11060];
    float* s_d2 = dbuf;            // [196 pos][36]  (d2: 14x14x32, no spatial pad)
    float* s_d1 = dbuf + 7056;     // padded 9x9 rows x 36 (d1: 7x7x32)
    float* s_in = dbuf + 9972;     // [16 pos][68]
    float* sP   = dbuf + 7056;     // P[16 taps][196 pos] aliases s_d1+s_in after deconv2

    const int n = blockIdx.x, tid = threadIdx.x;
    const int wv = __builtin_amdgcn_readfirstlane((int)(tid >> 6));
    const int lane = tid & 63;
    const int co0 = wv * 8;

    {
        float4* z1 = (float4*)(dbuf + 7056);
        for (int i = tid; i < 729; i += 256) z1[i] = make_float4(0.f, 0.f, 0.f, 0.f);
        for (int t = tid; t < 1024; t += 256) {
            int c = t & 63, p = t >> 6;
            s_in[p * 68 + c] = hin[(size_t)n * 1024 + c * 16 + p];
        }
    }
    __syncthreads();

    // ---- deconv1: ConvT 64->32 k3 s2 p1, 4x4 -> 7x7, relu ----
    {
        const int cig = lane & 7, pq = (lane >> 3) & 1, poff = lane >> 4;
        const int ci0 = cig * 8;
        const int ca = co0 + pq * 4;
        float bd[4];
        #pragma unroll
        for (int u = 0; u < 4; ++u) bd[u] = b_d1[ca + u];

        #pragma unroll
        for (int py = 0; py < 2; ++py) {
            #pragma unroll
            for (int px = 0; px < 2; ++px) {
                const int ny = 4 - py, nx = 4 - px;
                const int P = ny * nx;
                const int na = py ? 2 : 1, nb = px ? 2 : 1;
                float4 wd[4][2][2][2];
                #pragma unroll
                for (int u = 0; u < 4; ++u)
                    #pragma unroll
                    for (int a = 0; a < 2; ++a) {
                        if (a >= na) continue;
                        #pragma unroll
                        for (int b = 0; b < 2; ++b) {
                            if (b >= nb) continue;
                            int ky = py ? (a ? 2 : 0) : 1;
                            int kx = px ? (b ? 2 : 0) : 1;
                            const float* wp = wtd1 + ((ca + u) * 9 + ky * 3 + kx) * 64 + ci0;
                            wd[u][a][b][0] = *(const float4*)(wp);
                            wd[u][a][b][1] = *(const float4*)(wp + 4);
                        }
                    }
                const int niter = (P + 3) >> 2;
                for (int it = 0; it < niter; ++it) {
                    int pidx = it * 4 + poff;
                    bool act = pidx < P;
                    int p = act ? pidx : 0;
                    int sy = p / nx, sx = p - sy * nx;
                    float acc[4] = {};
                    #pragma unroll
                    for (int a = 0; a < 2; ++a) {
                        if (a >= na) continue;
                        int iy = py ? (a ? sy : sy + 1) : sy;
                        #pragma unroll
                        for (int b = 0; b < 2; ++b) {
                            if (b >= nb) continue;
                            int ix = px ? (b ? sx : sx + 1) : sx;
                            const float* bp = s_in + (iy * 4 + ix) * 68 + ci0;
                            float4 v0 = *(const float4*)(bp);
                            float4 v1 = *(const float4*)(bp + 4);
                            #pragma unroll
                            for (int u = 0; u < 4; ++u) {
                                dot4a(acc[u], v0, wd[u][a][b][0]);
                                dot4a(acc[u], v1, wd[u][a][b][1]);
                            }
                        }
                    }
                    #pragma unroll
                    for (int u = 0; u < 4; ++u) {
                        acc[u] += __shfl_xor(acc[u], 1);
                        acc[u] += __shfl_xor(acc[u], 2);
                        acc[u] += __shfl_xor(acc[u], 4);
                    }
                    if (cig == 0 && act) {
                        int oy = 2 * sy + py, ox = 2 * sx + px;
                        float4 o;
                        o.x = fmaxf(acc[0] + bd[0], 0.f);
                        o.y = fmaxf(acc[1] + bd[1], 0.f);
                        o.z = fmaxf(acc[2] + bd[2], 0.f);
                        o.w = fmaxf(acc[3] + bd[3], 0.f);
                        *(float4*)(s_d1 + ((oy + 1) * 9 + ox + 1) * 36 + ca) = o;
                    }
                }
            }
        }
    }
    __syncthreads();

    // ---- deconv2: ConvT 32->32 k4 s2 p1, 7x7 -> 14x14, relu ----
    {
        const int cig = lane & 3, pq = (lane >> 2) & 1;
        const int py = (lane >> 3) & 1, px = (lane >> 4) & 1, poff = lane >> 5;
        const int ci0 = cig * 8;
        const int ca = co0 + pq * 4;
        float4 w2[4][2][2][2];
        float bd[4];
        #pragma unroll
        for (int u = 0; u < 4; ++u) {
            bd[u] = b_d2[ca + u];
            #pragma unroll
            for (int a = 0; a < 2; ++a)
                #pragma unroll
                for (int b = 0; b < 2; ++b) {
                    int ky = py ? (a ? 2 : 0) : (a ? 3 : 1);
                    int kx = px ? (b ? 2 : 0) : (b ? 3 : 1);
                    const float* wp = wtd2 + ((ca + u) * 16 + ky * 4 + kx) * 32 + ci0;
                    w2[u][a][b][0] = *(const float4*)(wp);
                    w2[u][a][b][1] = *(const float4*)(wp + 4);
                }
        }
        for (int it = 0; it < 25; ++it) {
            int pidx = it * 2 + poff;
            bool act = pidx < 49;
            int sp = act ? pidx : 0;
            int sy = sp / 7, sx = sp - sy * 7;
            float acc[4] = {};
            #pragma unroll
            for (int a = 0; a < 2; ++a) {
                int iy = py ? (a ? sy : sy + 1) : (a ? sy - 1 : sy);
                #pragma unroll
                for (int b = 0; b < 2; ++b) {
                    int ix = px ? (b ? sx : sx + 1) : (b ? sx - 1 : sx);
                    const float* bp = s_d1 + ((iy + 1) * 9 + ix + 1) * 36 + ci0;
                    float4 v0 = *(const float4*)(bp);
                    float4 v1 = *(const float4*)(bp + 4);
                    #pragma unroll
                    for (int u = 0; u < 4; ++u) {
                        dot4a(acc[u], v0, w2[u][a][b][0]);
                        dot4a(acc[u], v1, w2[u][a][b][1]);
                    }
                }
            }
            #pragma unroll
            for (int u = 0; u < 4; ++u) {
                acc[u] += __shfl_xor(acc[u], 1);
                acc[u] += __shfl_xor(acc[u], 2);
            }
            if (cig == 0 && act) {
                int oy = 2 * sy + py, ox = 2 * sx + px;
                float4 o;
                o.x = fmaxf(acc[0] + bd[0], 0.f);
                o.y = fmaxf(acc[1] + bd[1], 0.f);
                o.z = fmaxf(acc[2] + bd[2], 0.f);
                o.w = fmaxf(acc[3] + bd[3], 0.f);
                *(float4*)(s_d2 + (oy * 14 + ox) * 36 + ca) = o;
            }
        }
    }
    __syncthreads();

    // ---- deconv3 phase 1: P[t][pos] = sum_ci d2[ci,pos] * w3[ci,t] ----
    {
        const int pp = lane & 15, tq = lane >> 4;
        float4 w3[4][8];
        #pragma unroll
        for (int j = 0; j < 4; ++j)
            #pragma unroll
            for (int q = 0; q < 8; ++q)
                w3[j][q] = *(const float4*)(wtd3 + (tq * 4 + j) * 32 + q * 4);
        #pragma unroll
        for (int r = 0; r < 4; ++r) {
            int p = r * 64 + wv * 16 + pp;
            if (p < 196) {
                const float* bp = s_d2 + p * 36;
                float4 v[8];
                #pragma unroll
                for (int q = 0; q < 8; ++q) v[q] = *(const float4*)(bp + q * 4);
                #pragma unroll
                for (int j = 0; j < 4; ++j) {
                    float acc = 0.f;
                    #pragma unroll
                    for (int q = 0; q < 8; ++q) dot4a(acc, v[q], w3[j][q]);
                    sP[(tq * 4 + j) * 196 + p] = acc;
                }
            }
        }
    }
    __syncthreads();

    // ---- deconv3 phase 2: x_hat = sigmoid(b + 4 masked P lookups) ----
    {
        const float bd3 = b_d3[0];
        #pragma unroll
        for (int t = 0; t < 4; ++t) {
            int o = t * 256 + tid;
            if (o < 784) {
                int oy = o / 28, ox = o - oy * 28;
                int py = oy & 1, px = ox & 1, sy = oy >> 1, sx = ox >> 1;
                float acc = bd3;
                #pragma unroll
                for (int a = 0; a < 2; ++a) {
                    int ky = py ? (a ? 2 : 0) : (a ? 3 : 1);
                    int iy = py ? (a ? sy : sy + 1) : (a ? sy - 1 : sy);
                    bool vy = (unsigned)iy < 14u;
                    #pragma unroll
                    for (int b = 0; b < 2; ++b) {
                        int kx = px ? (b ? 2 : 0) : (b ? 3 : 1);
                        int ix = px ? (b ? sx : sx + 1) : (b ? sx - 1 : sx);
                        if (vy && (unsigned)ix < 14u)
                            acc += sP[(ky * 4 + kx) * 196 + iy * 14 + ix];
                    }
                }
                xhat[(size_t)n * 784 + o] = 1.f / (1.f + expf(-acc));
            }
        }
    }
}

extern "C" void kernel_launch(void* const* d_in, const int* in_sizes, int n_in,
                              void* d_out, int out_size, void* d_ws, size_t ws_size,
                              hipStream_t stream) {
    const float* x     = (const float*)d_in[0];
    const float* eps   = (const float*)d_in[1];
    const float* w_c1  = (const float*)d_in[2];
    const float* b_c1  = (const float*)d_in[3];
    const float* w_c2  = (const float*)d_in[4];
    const float* b_c2  = (const float*)d_in[5];
    const float* w_c3  = (const float*)d_in[6];
    const float* b_c3  = (const float*)d_in[7];
    const float* w_fc1 = (const float*)d_in[8];
    const float* b_fc1 = (const float*)d_in[9];
    const float* w_mu  = (const float*)d_in[10];
    const float* b_mu  = (const float*)d_in[11];
    const float* w_ls  = (const float*)d_in[12];
    const float* b_ls  = (const float*)d_in[13];
    const float* w_fc2 = (const float*)d_in[14];
    const float* b_fc2 = (const float*)d_in[15];
    const float* w_fc3 = (const float*)d_in[16];
    const float* b_fc3 = (const float*)d_in[17];
    const float* w_d1  = (const float*)d_in[18];
    const float* b_d1  = (const float*)d_in[19];
    const float* w_d2  = (const float*)d_in[20];
    const float* b_d2  = (const float*)d_in[21];
    const float* w_d3  = (const float*)d_in[22];
    const float* b_d3  = (const float*)d_in[23];

    float* out = (float*)d_out;
    float* x_hat  = out;                  // 4096*784
    float* mu_out = out + 4096 * 784;     // 4096*20
    float* ls_out = mu_out + 4096 * 20;   // 4096*20

    float* buf1 = (float*)d_ws;           // 4096*1024 (h3 / fc3 out); zlat reuses head
    float* buf2 = buf1 + 4096 * 1024;     // 4096*256  (fc1 out / fc2 out)
    float* zlat = buf1;                   // 4096*20, live only between mulsrev and fc2
    float* wt2  = buf2 + 4096 * 256;      // 16384
    float* wt3  = wt2 + 16384;            // 18432
    float* wtd1 = wt3 + 18432;            // 18432
    float* wtd2 = wtd1 + 18432;           // 16384
    float* wtd3 = wtd2 + 16384;           // 512

    tr_kernel<<<72, 256, 0, stream>>>(w_c2, w_c3, w_d1, w_d2, w_d3, wt2, wt3, wtd1, wtd2, wtd3);
    enc_kernel<<<BATCH, 256, 0, stream>>>(x, w_c1, b_c1, wt2, b_c2, wt3, b_c3, buf1);
    gemm_nt_bn32<true><<<dim3(256 / 32, BATCH / 64), 256, 0, stream>>>(buf1, w_fc1, b_fc1, buf2, BATCH, 256, 1024);
    mulsrev_kernel<<<(BATCH * 20) / 256, 256, 0, stream>>>(buf2, w_mu, b_mu, w_ls, b_ls, eps, mu_out, ls_out, zlat);
    fc2_kernel<<<BATCH, 256, 0, stream>>>(zlat, w_fc2, b_fc2, buf2);
    gemm_nt<true><<<dim3(1024 / 64, BATCH / 64), 256, 0, stream>>>(buf2, w_fc3, b_fc3, buf1, BATCH, 1024, 256);
    dec_kernel<<<BATCH, 256, 0, stream>>>(buf1, wtd1, b_d1, wtd2, b_d2, wtd3, b_d3, x_hat);
}

// Round 11
// 636.099 us; speedup vs baseline: 1.1730x; 1.0105x over previous
//
#include <hip/hip_runtime.h>
#include <math.h>

#define BATCH 4096

__device__ __forceinline__ void dot4a(float& acc, const float4 v, const float4 wt) {
    acc = fmaf(v.x, wt.x, acc);
    acc = fmaf(v.y, wt.y, acc);
    acc = fmaf(v.z, wt.z, acc);
    acc = fmaf(v.w, wt.w, acc);
}

// ======================= weight transpose pre-pass =======================
__global__ __launch_bounds__(256) void tr_kernel(
    const float* __restrict__ w_c2, const float* __restrict__ w_c3,
    const float* __restrict__ w_d1, const float* __restrict__ w_d2,
    const float* __restrict__ w_d3,
    float* __restrict__ wt2, float* __restrict__ wt3,
    float* __restrict__ wtd1, float* __restrict__ wtd2, float* __restrict__ wtd3)
{
    int i = blockIdx.x * 256 + threadIdx.x;
    if (i < 16384) {  // w_c2 [32][32][16] -> wt2[(co*16+tap)*32+ci]
        int ci = i & 31, tap = (i >> 5) & 15, co = i >> 9;
        wt2[i] = w_c2[(co * 32 + ci) * 16 + tap];
    }
    if (i < 18432) {  // w_c3 [64][32][9] -> wt3[(co*9+tap)*32+ci]
        int ci = i & 31, r = i >> 5, tap = r % 9, co = r / 9;
        wt3[i] = w_c3[(co * 32 + ci) * 9 + tap];
    }
    if (i < 18432) {  // w_d1 [64][32][9] -> wtd1[(co*9+tap)*64+ci]
        int ci = i & 63, r = i >> 6, tap = r % 9, co = r / 9;
        wtd1[i] = w_d1[(ci * 32 + co) * 9 + tap];
    }
    if (i < 16384) {  // w_d2 [32][32][16] -> wtd2[(co*16+tap)*32+ci]
        int ci = i & 31, tap = (i >> 5) & 15, co = i >> 9;
        wtd2[i] = w_d2[(ci * 32 + co) * 16 + tap];
    }
    if (i < 512) {    // w_d3 [32][1][16] -> wtd3[tap*32+ci]
        int ci = i & 31, tap = i >> 5;
        wtd3[i] = w_d3[ci * 16 + tap];
    }
}

// ======================= fused encoder (best measured config) =======================
__global__ __launch_bounds__(256, 3) void enc_kernel(
    const float* __restrict__ x,
    const float* __restrict__ w_c1, const float* __restrict__ b_c1,
    const float* __restrict__ wt2, const float* __restrict__ b_c2,
    const float* __restrict__ wt3, const float* __restrict__ b_c3,
    float* __restrict__ h3out)
{
    __shared__ __align__(16) float buf[12708];
    float* s_h1 = buf;            // padded 16x16 rows x 36  (h1: 14x14x32)
    float* s_h3 = buf;            // [1024] aliases h1 after conv2
    float* s_x  = buf + 9216;     // padded 30x30            (x: 28x28)
    float* s_h2 = buf + 10116;    // padded 9x9 rows x 32    (h2: 7x7x32)

    const int n = blockIdx.x, tid = threadIdx.x;
    const int wv = __builtin_amdgcn_readfirstlane((int)(tid >> 6));
    const int lane = tid & 63;
    const int co0 = wv * 8;

    {
        float4* z1 = (float4*)buf;
        #pragma unroll
        for (int i = tid; i < 2304; i += 256) z1[i] = make_float4(0.f, 0.f, 0.f, 0.f);
        float4* z2 = (float4*)(buf + 10116);
        for (int i = tid; i < 648; i += 256) z2[i] = make_float4(0.f, 0.f, 0.f, 0.f);
        for (int i = tid; i < 30; i += 256) { s_x[i] = 0.f; s_x[870 + i] = 0.f; }
        for (int i = tid; i < 28; i += 256) { s_x[(i + 1) * 30] = 0.f; s_x[(i + 1) * 30 + 29] = 0.f; }
        for (int i = tid; i < 784; i += 256) {
            int iy = i / 28, ix = i - iy * 28;
            s_x[(iy + 1) * 30 + ix + 1] = x[(size_t)n * 784 + i];
        }
    }
    __syncthreads();

    // ---- conv1 ----
    {
        const int poff = lane & 15, pr = lane >> 4;
        const int ca = co0 + pr * 2;
        float w1a[16], w1b[16];
        #pragma unroll
        for (int k = 0; k < 4; ++k) {
            *(float4*)&w1a[4 * k] = *(const float4*)(w_c1 + ca * 16 + 4 * k);
            *(float4*)&w1b[4 * k] = *(const float4*)(w_c1 + (ca + 1) * 16 + 4 * k);
        }
        const float ba = b_c1[ca], bb = b_c1[ca + 1];
        for (int t = 0; t < 13; ++t) {
            int pos = poff + 16 * t;
            bool val = pos < 196;
            int p = val ? pos : 0;
            int oy = p / 14, ox = p - oy * 14;
            const float* bp = s_x + (2 * oy) * 30 + 2 * ox;
            float a0 = ba, a1 = bb;
            #pragma unroll
            for (int ky = 0; ky < 4; ++ky)
                #pragma unroll
                for (int kx = 0; kx < 4; ++kx) {
                    float v = bp[ky * 30 + kx];
                    a0 = fmaf(v, w1a[ky * 4 + kx], a0);
                    a1 = fmaf(v, w1b[ky * 4 + kx], a1);
                }
            if (val)
                *(float2*)(s_h1 + ((oy + 1) * 16 + ox + 1) * 36 + ca) =
                    make_float2(fmaxf(a0, 0.f), fmaxf(a1, 0.f));
        }
    }
    __syncthreads();

    // ---- conv2 ----
    {
        const int parity = lane & 1, pr = (lane >> 1) & 3, cig = lane >> 3;
        const int ca = co0 + pr * 2;
        float4 w2a[16], w2b[16];
        #pragma unroll
        for (int t = 0; t < 16; ++t) {
            w2a[t] = *(const float4*)(wt2 + (ca * 16 + t) * 32 + cig * 4);
            w2b[t] = *(const float4*)(wt2 + ((ca + 1) * 16 + t) * 32 + cig * 4);
        }
        const float ba = b_c2[ca], bb = b_c2[ca + 1];
        for (int t = 0; t < 25; ++t) {
            int pos = parity + 2 * t;
            bool val = pos < 49;
            int p = val ? pos : 0;
            int oy = p / 7, ox = p - oy * 7;
            const float* bp = s_h1 + ((2 * oy) * 16 + 2 * ox) * 36 + cig * 4;
            float a0 = 0.f, a1 = 0.f;
            #pragma unroll
            for (int ky = 0; ky < 4; ++ky)
                #pragma unroll
                for (int kx = 0; kx < 4; ++kx) {
                    float4 v = *(const float4*)(bp + (ky * 16 + kx) * 36);
                    dot4a(a0, v, w2a[ky * 4 + kx]);
                    dot4a(a1, v, w2b[ky * 4 + kx]);
                }
            a0 += __shfl_xor(a0, 8);  a1 += __shfl_xor(a1, 8);
            a0 += __shfl_xor(a0, 16); a1 += __shfl_xor(a1, 16);
            a0 += __shfl_xor(a0, 32); a1 += __shfl_xor(a1, 32);
            if (cig == 0 && val)
                *(float2*)(s_h2 + ((oy + 1) * 9 + ox + 1) * 32 + ca) =
                    make_float2(fmaxf(a0 + ba, 0.f), fmaxf(a1 + bb, 0.f));
        }
    }
    __syncthreads();

    // ---- conv3 ----
    {
        const int pr = lane & 7, cig = lane >> 3;
        const int ca = wv * 16 + pr * 2;
        float4 w3a[9], w3b[9];
        #pragma unroll
        for (int t = 0; t < 9; ++t) {
            w3a[t] = *(const float4*)(wt3 + (ca * 9 + t) * 32 + cig * 4);
            w3b[t] = *(const float4*)(wt3 + ((ca + 1) * 9 + t) * 32 + cig * 4);
        }
        const float ba = b_c3[ca], bb = b_c3[ca + 1];
        #pragma unroll 2
        for (int pos = 0; pos < 16; ++pos) {
            int oy = pos >> 2, ox = pos & 3;
            const float* bp = s_h2 + ((2 * oy) * 9 + 2 * ox) * 32 + cig * 4;
            float a0 = 0.f, a1 = 0.f;
            #pragma unroll
            for (int ky = 0; ky < 3; ++ky)
                #pragma unroll
                for (int kx = 0; kx < 3; ++kx) {
                    float4 v = *(const float4*)(bp + (ky * 9 + kx) * 32);
                    dot4a(a0, v, w3a[ky * 3 + kx]);
                    dot4a(a1, v, w3b[ky * 3 + kx]);
                }
            a0 += __shfl_xor(a0, 8);  a1 += __shfl_xor(a1, 8);
            a0 += __shfl_xor(a0, 16); a1 += __shfl_xor(a1, 16);
            a0 += __shfl_xor(a0, 32); a1 += __shfl_xor(a1, 32);
            if (cig == 0) {
                s_h3[ca * 16 + pos] = fmaxf(a0 + ba, 0.f);
                s_h3[(ca + 1) * 16 + pos] = fmaxf(a1 + bb, 0.f);
            }
        }
    }
    __syncthreads();
    for (int i = tid; i < 1024; i += 256) h3out[(size_t)n * 1024 + i] = s_h3[i];
}

// ======================= tiled NT SGEMM (64x64, 256 thr, BK=16) =======================
template <bool RELU>
__global__ __launch_bounds__(256) void gemm_nt(
    const float* __restrict__ A, const float* __restrict__ W,
    const float* __restrict__ bias, float* __restrict__ C,
    int M, int N, int K)
{
    __shared__ float As[16][65];
    __shared__ float Ws[16][65];
    const int tid = threadIdx.x;
    const int col0 = blockIdx.x * 64;
    const int row0 = blockIdx.y * 64;
    const int tx = tid & 15, ty = tid >> 4;
    const int lr = tid >> 2, lc = (tid & 3) * 4;
    float acc[4][4] = {};

    for (int k0 = 0; k0 < K; k0 += 16) {
        float4 av = *(const float4*)(A + (size_t)(row0 + lr) * K + k0 + lc);
        float4 wv = *(const float4*)(W + (size_t)(col0 + lr) * K + k0 + lc);
        As[lc + 0][lr] = av.x; As[lc + 1][lr] = av.y; As[lc + 2][lr] = av.z; As[lc + 3][lr] = av.w;
        Ws[lc + 0][lr] = wv.x; Ws[lc + 1][lr] = wv.y; Ws[lc + 2][lr] = wv.z; Ws[lc + 3][lr] = wv.w;
        __syncthreads();
        #pragma unroll
        for (int kk = 0; kk < 16; ++kk) {
            float a[4], b[4];
            #pragma unroll
            for (int i = 0; i < 4; ++i) a[i] = As[kk][ty * 4 + i];
            #pragma unroll
            for (int j = 0; j < 4; ++j) b[j] = Ws[kk][tx * 4 + j];
            #pragma unroll
            for (int i = 0; i < 4; ++i)
                #pragma unroll
                for (int j = 0; j < 4; ++j)
                    acc[i][j] = fmaf(a[i], b[j], acc[i][j]);
        }
        __syncthreads();
    }
    #pragma unroll
    for (int i = 0; i < 4; ++i) {
        int row = row0 + ty * 4 + i;
        float* cp = C + (size_t)row * N + col0 + tx * 4;
        float4 v;
        v.x = acc[i][0] + bias[col0 + tx * 4 + 0];
        v.y = acc[i][1] + bias[col0 + tx * 4 + 1];
        v.z = acc[i][2] + bias[col0 + tx * 4 + 2];
        v.w = acc[i][3] + bias[col0 + tx * 4 + 3];
        if (RELU) {
            v.x = fmaxf(v.x, 0.f); v.y = fmaxf(v.y, 0.f);
            v.z = fmaxf(v.z, 0.f); v.w = fmaxf(v.w, 0.f);
        }
        *(float4*)cp = v;
    }
}

// ======================= NT SGEMM, 64x32 tile (fc1: 512 blocks, 2/CU) =======================
template <bool RELU>
__global__ __launch_bounds__(256) void gemm_nt_bn32(
    const float* __restrict__ A, const float* __restrict__ W,
    const float* __restrict__ bias, float* __restrict__ C,
    int M, int N, int K)
{
    __shared__ float As[16][65];
    __shared__ float Ws[16][33];
    const int tid = threadIdx.x;
    const int col0 = blockIdx.x * 32;
    const int row0 = blockIdx.y * 64;
    const int tx = tid & 7, ty = tid >> 3;
    const int lr = tid >> 2, lc = (tid & 3) * 4;
    float acc[2][4] = {};

    for (int k0 = 0; k0 < K; k0 += 16) {
        float4 av = *(const float4*)(A + (size_t)(row0 + lr) * K + k0 + lc);
        As[lc + 0][lr] = av.x; As[lc + 1][lr] = av.y; As[lc + 2][lr] = av.z; As[lc + 3][lr] = av.w;
        if (tid < 128) {
            float4 wv = *(const float4*)(W + (size_t)(col0 + lr) * K + k0 + lc);
            Ws[lc + 0][lr] = wv.x; Ws[lc + 1][lr] = wv.y; Ws[lc + 2][lr] = wv.z; Ws[lc + 3][lr] = wv.w;
        }
        __syncthreads();
        #pragma unroll
        for (int kk = 0; kk < 16; ++kk) {
            float a0 = As[kk][ty * 2], a1 = As[kk][ty * 2 + 1];
            float b[4];
            #pragma unroll
            for (int j = 0; j < 4; ++j) b[j] = Ws[kk][tx * 4 + j];
            #pragma unroll
            for (int j = 0; j < 4; ++j) {
                acc[0][j] = fmaf(a0, b[j], acc[0][j]);
                acc[1][j] = fmaf(a1, b[j], acc[1][j]);
            }
        }
        __syncthreads();
    }
    #pragma unroll
    for (int i = 0; i < 2; ++i) {
        int row = row0 + ty * 2 + i;
        float* cp = C + (size_t)row * N + col0 + tx * 4;
        float4 v;
        v.x = acc[i][0] + bias[col0 + tx * 4 + 0];
        v.y = acc[i][1] + bias[col0 + tx * 4 + 1];
        v.z = acc[i][2] + bias[col0 + tx * 4 + 2];
        v.w = acc[i][3] + bias[col0 + tx * 4 + 3];
        if (RELU) {
            v.x = fmaxf(v.x, 0.f); v.y = fmaxf(v.y, 0.f);
            v.z = fmaxf(v.z, 0.f); v.w = fmaxf(v.w, 0.f);
        }
        *(float4*)cp = v;
    }
}

// ==== fused latent: mu/ls heads + 100-step reversing + reparam + fc2 ====
// Block = 16 images. h + w_fc2 staged in LDS; z never touches HBM.
__global__ __launch_bounds__(256) void latent_kernel(
    const float* __restrict__ h,
    const float* __restrict__ w_mu, const float* __restrict__ b_mu,
    const float* __restrict__ w_ls, const float* __restrict__ b_ls,
    const float* __restrict__ eps, const float* __restrict__ w_fc2,
    const float* __restrict__ b_fc2,
    float* __restrict__ mu_out, float* __restrict__ ls_out,
    float* __restrict__ fc2_out)
{
    __shared__ __align__(16) float sh[16 * 256];   // h tile
    __shared__ __align__(16) float sw[256 * 20];   // w_fc2
    __shared__ float sz[16 * 20];                  // z
    const int tid = threadIdx.x, blk = blockIdx.x;
    const size_t base = (size_t)blk * 16 * 256;

    {
        float4* shv = (float4*)sh;
        const float4* hv = (const float4*)(h + base);
        #pragma unroll
        for (int k = tid; k < 1024; k += 256) shv[k] = hv[k];
        float4* swv = (float4*)sw;
        const float4* wv = (const float4*)w_fc2;
        #pragma unroll
        for (int k = tid; k < 1280; k += 256) swv[k] = wv[k];
    }
    __syncthreads();

    // phase A: 320 items (16 img x 20 latents)
    for (int item = tid; item < 320; item += 256) {
        int i = item / 20, j = item - i * 20;
        const float4* hp = (const float4*)(sh + i * 256);
        const float4* mp = (const float4*)(w_mu + j * 256);
        const float4* lp = (const float4*)(w_ls + j * 256);
        float am = b_mu[j], al = b_ls[j];
        #pragma unroll 8
        for (int k = 0; k < 64; ++k) {
            float4 hv = hp[k], mv = mp[k], lv = lp[k];
            am = fmaf(hv.x, mv.x, am); al = fmaf(hv.x, lv.x, al);
            am = fmaf(hv.y, mv.y, am); al = fmaf(hv.y, lv.y, al);
            am = fmaf(hv.z, mv.z, am); al = fmaf(hv.z, lv.z, al);
            am = fmaf(hv.w, mv.w, am); al = fmaf(hv.w, lv.w, al);
        }
        int gidx = blk * 320 + item;
        mu_out[gidx] = am;
        ls_out[gidx] = al;
        double m = (double)am;
        float s = al;
        #pragma unroll 4
        for (int t = 0; t < 100; ++t) {
            m += 0.1 * m;
            s += 0.05f * (expf(s) - 1.f);
        }
        sz[item] = fmaf(eps[gidx], expf(0.5f * s), (float)m);
    }
    __syncthreads();

    // phase B: fc2 -- 16 img x 256 outputs, relu
    #pragma unroll 4
    for (int k = 0; k < 16; ++k) {
        int o = k * 256 + tid;
        int i = o >> 8, j = o & 255;
        float acc = b_fc2[j];
        const float* zp = sz + i * 20;
        const float* wp = sw + j * 20;
        #pragma unroll
        for (int q = 0; q < 20; ++q) acc = fmaf(zp[q], wp[q], acc);
        fc2_out[base + o] = fmaxf(acc, 0.f);
    }
}

// ======================= fused decoder (best measured config) =======================
__global__ __launch_bounds__(256, 3) void dec_kernel(
    const float* __restrict__ hin,
    const float* __restrict__ wtd1, const float* __restrict__ b_d1,
    const float* __restrict__ wtd2, const float* __restrict__ b_d2,
    const float* __restrict__ wtd3, const float* __restrict__ b_d3,
    float* __restrict__ xhat)
{
    __shared__ __align__(16) float dbuf[11060];
    float* s_d2 = dbuf;            // [196 pos][36]
    float* s_d1 = dbuf + 7056;     // padded 9x9 rows x 36
    float* s_in = dbuf + 9972;     // [16 pos][68]
    float* sP   = dbuf + 7056;     // P[16][196] aliases d1+s_in after deconv2

    const int n = blockIdx.x, tid = threadIdx.x;
    const int wv = __builtin_amdgcn_readfirstlane((int)(tid >> 6));
    const int lane = tid & 63;
    const int co0 = wv * 8;

    {
        float4* z1 = (float4*)(dbuf + 7056);
        for (int i = tid; i < 729; i += 256) z1[i] = make_float4(0.f, 0.f, 0.f, 0.f);
        for (int t = tid; t < 1024; t += 256) {
            int c = t & 63, p = t >> 6;
            s_in[p * 68 + c] = hin[(size_t)n * 1024 + c * 16 + p];
        }
    }
    __syncthreads();

    // ---- deconv1 ----
    {
        const int cig = lane & 7, pq = (lane >> 3) & 1, poff = lane >> 4;
        const int ci0 = cig * 8;
        const int ca = co0 + pq * 4;
        float bd[4];
        #pragma unroll
        for (int u = 0; u < 4; ++u) bd[u] = b_d1[ca + u];

        #pragma unroll
        for (int py = 0; py < 2; ++py) {
            #pragma unroll
            for (int px = 0; px < 2; ++px) {
                const int ny = 4 - py, nx = 4 - px;
                const int P = ny * nx;
                const int na = py ? 2 : 1, nb = px ? 2 : 1;
                float4 wd[4][2][2][2];
                #pragma unroll
                for (int u = 0; u < 4; ++u)
                    #pragma unroll
                    for (int a = 0; a < 2; ++a) {
                        if (a >= na) continue;
                        #pragma unroll
                        for (int b = 0; b < 2; ++b) {
                            if (b >= nb) continue;
                            int ky = py ? (a ? 2 : 0) : 1;
                            int kx = px ? (b ? 2 : 0) : 1;
                            const float* wp = wtd1 + ((ca + u) * 9 + ky * 3 + kx) * 64 + ci0;
                            wd[u][a][b][0] = *(const float4*)(wp);
                            wd[u][a][b][1] = *(const float4*)(wp + 4);
                        }
                    }
                const int niter = (P + 3) >> 2;
                for (int it = 0; it < niter; ++it) {
                    int pidx = it * 4 + poff;
                    bool act = pidx < P;
                    int p = act ? pidx : 0;
                    int sy = p / nx, sx = p - sy * nx;
                    float acc[4] = {};
                    #pragma unroll
                    for (int a = 0; a < 2; ++a) {
                        if (a >= na) continue;
                        int iy = py ? (a ? sy : sy + 1) : sy;
                        #pragma unroll
                        for (int b = 0; b < 2; ++b) {
                            if (b >= nb) continue;
                            int ix = px ? (b ? sx : sx + 1) : sx;
                            const float* bp = s_in + (iy * 4 + ix) * 68 + ci0;
                            float4 v0 = *(const float4*)(bp);
                            float4 v1 = *(const float4*)(bp + 4);
                            #pragma unroll
                            for (int u = 0; u < 4; ++u) {
                                dot4a(acc[u], v0, wd[u][a][b][0]);
                                dot4a(acc[u], v1, wd[u][a][b][1]);
                            }
                        }
                    }
                    #pragma unroll
                    for (int u = 0; u < 4; ++u) {
                        acc[u] += __shfl_xor(acc[u], 1);
                        acc[u] += __shfl_xor(acc[u], 2);
                        acc[u] += __shfl_xor(acc[u], 4);
                    }
                    if (cig == 0 && act) {
                        int oy = 2 * sy + py, ox = 2 * sx + px;
                        float4 o;
                        o.x = fmaxf(acc[0] + bd[0], 0.f);
                        o.y = fmaxf(acc[1] + bd[1], 0.f);
                        o.z = fmaxf(acc[2] + bd[2], 0.f);
                        o.w = fmaxf(acc[3] + bd[3], 0.f);
                        *(float4*)(s_d1 + ((oy + 1) * 9 + ox + 1) * 36 + ca) = o;
                    }
                }
            }
        }
    }
    __syncthreads();

    // ---- deconv2 ----
    {
        const int cig = lane & 3, pq = (lane >> 2) & 1;
        const int py = (lane >> 3) & 1, px = (lane >> 4) & 1, poff = lane >> 5;
        const int ci0 = cig * 8;
        const int ca = co0 + pq * 4;
        float4 w2[4][2][2][2];
        float bd[4];
        #pragma unroll
        for (int u = 0; u < 4; ++u) {
            bd[u] = b_d2[ca + u];
            #pragma unroll
            for (int a = 0; a < 2; ++a)
                #pragma unroll
                for (int b = 0; b < 2; ++b) {
                    int ky = py ? (a ? 2 : 0) : (a ? 3 : 1);
                    int kx = px ? (b ? 2 : 0) : (b ? 3 : 1);
                    const float* wp = wtd2 + ((ca + u) * 16 + ky * 4 + kx) * 32 + ci0;
                    w2[u][a][b][0] = *(const float4*)(wp);
                    w2[u][a][b][1] = *(const float4*)(wp + 4);
                }
        }
        for (int it = 0; it < 25; ++it) {
            int pidx = it * 2 + poff;
            bool act = pidx < 49;
            int sp = act ? pidx : 0;
            int sy = sp / 7, sx = sp - sy * 7;
            float acc[4] = {};
            #pragma unroll
            for (int a = 0; a < 2; ++a) {
                int iy = py ? (a ? sy : sy + 1) : (a ? sy - 1 : sy);
                #pragma unroll
                for (int b = 0; b < 2; ++b) {
                    int ix = px ? (b ? sx : sx + 1) : (b ? sx - 1 : sx);
                    const float* bp = s_d1 + ((iy + 1) * 9 + ix + 1) * 36 + ci0;
                    float4 v0 = *(const float4*)(bp);
                    float4 v1 = *(const float4*)(bp + 4);
                    #pragma unroll
                    for (int u = 0; u < 4; ++u) {
                        dot4a(acc[u], v0, w2[u][a][b][0]);
                        dot4a(acc[u], v1, w2[u][a][b][1]);
                    }
                }
            }
            #pragma unroll
            for (int u = 0; u < 4; ++u) {
                acc[u] += __shfl_xor(acc[u], 1);
                acc[u] += __shfl_xor(acc[u], 2);
            }
            if (cig == 0 && act) {
                int oy = 2 * sy + py, ox = 2 * sx + px;
                float4 o;
                o.x = fmaxf(acc[0] + bd[0], 0.f);
                o.y = fmaxf(acc[1] + bd[1], 0.f);
                o.z = fmaxf(acc[2] + bd[2], 0.f);
                o.w = fmaxf(acc[3] + bd[3], 0.f);
                *(float4*)(s_d2 + (oy * 14 + ox) * 36 + ca) = o;
            }
        }
    }
    __syncthreads();

    // ---- deconv3 phase 1 ----
    {
        const int pp = lane & 15, tq = lane >> 4;
        float4 w3[4][8];
        #pragma unroll
        for (int j = 0; j < 4; ++j)
            #pragma unroll
            for (int q = 0; q < 8; ++q)
                w3[j][q] = *(const float4*)(wtd3 + (tq * 4 + j) * 32 + q * 4);
        #pragma unroll
        for (int r = 0; r < 4; ++r) {
            int p = r * 64 + wv * 16 + pp;
            if (p < 196) {
                const float* bp = s_d2 + p * 36;
                float4 v[8];
                #pragma unroll
                for (int q = 0; q < 8; ++q) v[q] = *(const float4*)(bp + q * 4);
                #pragma unroll
                for (int j = 0; j < 4; ++j) {
                    float acc = 0.f;
                    #pragma unroll
                    for (int q = 0; q < 8; ++q) dot4a(acc, v[q], w3[j][q]);
                    sP[(tq * 4 + j) * 196 + p] = acc;
                }
            }
        }
    }
    __syncthreads();

    // ---- deconv3 phase 2 ----
    {
        const float bd3 = b_d3[0];
        #pragma unroll
        for (int t = 0; t < 4; ++t) {
            int o = t * 256 + tid;
            if (o < 784) {
                int oy = o / 28, ox = o - oy * 28;
                int py = oy & 1, px = ox & 1, sy = oy >> 1, sx = ox >> 1;
                float acc = bd3;
                #pragma unroll
                for (int a = 0; a < 2; ++a) {
                    int ky = py ? (a ? 2 : 0) : (a ? 3 : 1);
                    int iy = py ? (a ? sy : sy + 1) : (a ? sy - 1 : sy);
                    bool vy = (unsigned)iy < 14u;
                    #pragma unroll
                    for (int b = 0; b < 2; ++b) {
                        int kx = px ? (b ? 2 : 0) : (b ? 3 : 1);
                        int ix = px ? (b ? sx : sx + 1) : (b ? sx - 1 : sx);
                        if (vy && (unsigned)ix < 14u)
                            acc += sP[(ky * 4 + kx) * 196 + iy * 14 + ix];
                    }
                }
                xhat[(size_t)n * 784 + o] = 1.f / (1.f + expf(-acc));
            }
        }
    }
}

extern "C" void kernel_launch(void* const* d_in, const int* in_sizes, int n_in,
                              void* d_out, int out_size, void* d_ws, size_t ws_size,
                              hipStream_t stream) {
    const float* x     = (const float*)d_in[0];
    const float* eps   = (const float*)d_in[1];
    const float* w_c1  = (const float*)d_in[2];
    const float* b_c1  = (const float*)d_in[3];
    const float* w_c2  = (const float*)d_in[4];
    const float* b_c2  = (const float*)d_in[5];
    const float* w_c3  = (const float*)d_in[6];
    const float* b_c3  = (const float*)d_in[7];
    const float* w_fc1 = (const float*)d_in[8];
    const float* b_fc1 = (const float*)d_in[9];
    const float* w_mu  = (const float*)d_in[10];
    const float* b_mu  = (const float*)d_in[11];
    const float* w_ls  = (const float*)d_in[12];
    const float* b_ls  = (const float*)d_in[13];
    const float* w_fc2 = (const float*)d_in[14];
    const float* b_fc2 = (const float*)d_in[15];
    const float* w_fc3 = (const float*)d_in[16];
    const float* b_fc3 = (const float*)d_in[17];
    const float* w_d1  = (const float*)d_in[18];
    const float* b_d1  = (const float*)d_in[19];
    const float* w_d2  = (const float*)d_in[20];
    const float* b_d2  = (const float*)d_in[21];
    const float* w_d3  = (const float*)d_in[22];
    const float* b_d3  = (const float*)d_in[23];

    float* out = (float*)d_out;
    float* x_hat  = out;                  // 4096*784
    float* mu_out = out + 4096 * 784;     // 4096*20
    float* ls_out = mu_out + 4096 * 20;   // 4096*20

    float* buf1 = (float*)d_ws;           // 4096*1024 (h3 / fc3 out)
    float* buf2 = buf1 + 4096 * 1024;     // 4096*256  (fc1 out / fc2 out)
    float* wt2  = buf2 + 4096 * 256;      // 16384
    float* wt3  = wt2 + 16384;            // 18432
    float* wtd1 = wt3 + 18432;            // 18432
    float* wtd2 = wtd1 + 18432;           // 16384
    float* wtd3 = wtd2 + 16384;           // 512

    tr_kernel<<<72, 256, 0, stream>>>(w_c2, w_c3, w_d1, w_d2, w_d3, wt2, wt3, wtd1, wtd2, wtd3);
    enc_kernel<<<BATCH, 256, 0, stream>>>(x, w_c1, b_c1, wt2, b_c2, wt3, b_c3, buf1);
    gemm_nt_bn32<true><<<dim3(256 / 32, BATCH / 64), 256, 0, stream>>>(buf1, w_fc1, b_fc1, buf2, BATCH, 256, 1024);
    latent_kernel<<<BATCH / 16, 256, 0, stream>>>(buf2, w_mu, b_mu, w_ls, b_ls, eps, w_fc2, b_fc2,
                                                  mu_out, ls_out, buf2);
    gemm_nt<true><<<dim3(1024 / 64, BATCH / 64), 256, 0, stream>>>(buf2, w_fc3, b_fc3, buf1, BATCH, 1024, 256);
    dec_kernel<<<BATCH, 256, 0, stream>>>(buf1, wtd1, b_d1, wtd2, b_d2, wtd3, b_d3, x_hat);
}